// Round 4
// baseline (90.471 us; speedup 1.0000x reference)
//
#include <hip/hip_runtime.h>
#include <hip/hip_bf16.h>

#define NN  50000
#define DD  256
#define KNB 16
#define BM  64
#define NSL 8      // column slices (one per XCD)
#define SLW 32     // slice width in columns (64B bf16 rows -> line-pure slices)
#define NKT 8      // 256 / 32

typedef __attribute__((ext_vector_type(8))) short bf16x8;
typedef __attribute__((ext_vector_type(4))) float f32x4;

static __device__ __forceinline__ float bf2f(unsigned int u16) {
    union { unsigned int i; float f; } c; c.i = u16 << 16; return c.f;
}
static __device__ __forceinline__ float bf2f_hi(unsigned int u) {
    union { unsigned int i; float f; } c; c.i = u & 0xffff0000u; return c.f;
}
static __device__ __forceinline__ short f2bf(float f) {
    union { float f; unsigned int i; } c; c.f = f;
    unsigned int r = c.i + 0x7FFFu + ((c.i >> 16) & 1u);   // RNE
    return (short)(r >> 16);
}

// ---------------------------------------------------------------------------
// Kernel 0: W (f32, row-major 256x256) -> bf16 fragment-tiled Wbf.
// slot s = ((kt*16 + nb)*4 + kb)*16 + j  holds 8 bf16:
//   Wbf[s*8 + e] = W[nb*16 + j][kt*32 + kb*8 + e]
// ---------------------------------------------------------------------------
__global__ void convert_w(const float* __restrict__ W, unsigned short* __restrict__ Wbf)
{
    int s = blockIdx.x * blockDim.x + threadIdx.x;   // 8192 slots
    if (s >= 8192) return;
    int j  = s & 15;
    int kb = (s >> 4) & 3;
    int nb = (s >> 6) & 15;
    int kt = s >> 10;
    const float4* p = (const float4*)(W + (nb * 16 + j) * DD + kt * 32 + kb * 8);
    float4 a = p[0], b = p[1];
    bf16x8 v;
    v[0]=f2bf(a.x); v[1]=f2bf(a.y); v[2]=f2bf(a.z); v[3]=f2bf(a.w);
    v[4]=f2bf(b.x); v[5]=f2bf(b.y); v[6]=f2bf(b.z); v[7]=f2bf(b.w);
    *(bf16x8*)&Wbf[(size_t)s * 8] = v;
}

// ---------------------------------------------------------------------------
// Kernel 1: x = relu(feats @ W^T + b) -> bf16, written in SLICED layout:
//   xs[(col>>5)*NN*32 + row*32 + (col&31)]
// 256 threads = 4 waves; wave wc owns cols [wc*64, wc*64+64).
// W panel lives in 128 VGPRs per wave (preloaded from Wbf). A fragments are
// loaded per-lane directly from global (each feats line read once per block;
// L1 absorbs the 4-wave overlap). NO LDS, NO barriers.
// ---------------------------------------------------------------------------
__global__ __launch_bounds__(256, 2) void gemm_relu(
    const float* __restrict__ feats, const unsigned short* __restrict__ Wbf,
    const float* __restrict__ bias, unsigned short* __restrict__ xs)
{
    const int tid  = threadIdx.x;
    const int lane = tid & 63;
    const int wc   = tid >> 6;
    const int l15  = lane & 15;
    const int lg   = lane >> 4;
    const int blockRow = blockIdx.x * BM;

    // ---- W panel -> registers: wreg[n][kt] ----
    bf16x8 wreg[4][NKT];
    #pragma unroll
    for (int n = 0; n < 4; ++n)
        #pragma unroll
        for (int kt = 0; kt < NKT; ++kt) {
            int idx = ((kt * 16 + wc * 4 + n) * 4 + lg) * 16 + l15;
            wreg[n][kt] = *(const bf16x8*)(Wbf + (size_t)idx * 8);
        }

    // ---- A row pointers (clamped; garbage rows masked at store) ----
    const float* aptr[4];
    #pragma unroll
    for (int m = 0; m < 4; ++m) {
        int r = blockRow + m * 16 + l15;
        if (r > NN - 1) r = NN - 1;
        aptr[m] = feats + (size_t)r * DD + lg * 8;
    }

    float bv[4];
    #pragma unroll
    for (int n = 0; n < 4; ++n) bv[n] = bias[wc * 64 + n * 16 + l15];

    f32x4 acc[4][4];
    #pragma unroll
    for (int m = 0; m < 4; ++m)
        #pragma unroll
        for (int n = 0; n < 4; ++n) acc[m][n] = (f32x4)0.0f;

    #pragma unroll
    for (int kt = 0; kt < NKT; ++kt) {
        bf16x8 afr[4];
        #pragma unroll
        for (int m = 0; m < 4; ++m) {
            f32x4 lo = *(const f32x4*)(aptr[m] + kt * 32);
            f32x4 hi = *(const f32x4*)(aptr[m] + kt * 32 + 4);
            union { __hip_bfloat162 h[4]; bf16x8 v; } u;
            u.h[0] = __float22bfloat162_rn(make_float2(lo[0], lo[1]));
            u.h[1] = __float22bfloat162_rn(make_float2(lo[2], lo[3]));
            u.h[2] = __float22bfloat162_rn(make_float2(hi[0], hi[1]));
            u.h[3] = __float22bfloat162_rn(make_float2(hi[2], hi[3]));
            afr[m] = u.v;
        }
        #pragma unroll
        for (int m = 0; m < 4; ++m)
            #pragma unroll
            for (int n = 0; n < 4; ++n)
                acc[m][n] = __builtin_amdgcn_mfma_f32_16x16x32_bf16(
                    afr[m], wreg[n][kt], acc[m][n], 0, 0, 0);
    }

    // ---- epilogue: bias + relu -> sliced bf16 store ----
    #pragma unroll
    for (int n = 0; n < 4; ++n) {
        const int sl = wc * 2 + (n >> 1);
        const int c  = (n & 1) * 16 + l15;
        unsigned short* xb = xs + (size_t)sl * NN * SLW + c;
        #pragma unroll
        for (int m = 0; m < 4; ++m) {
            int rbase = blockRow + m * 16 + (lg << 2);
            f32x4 a = acc[m][n];
            #pragma unroll
            for (int r = 0; r < 4; ++r) {
                int row = rbase + r;
                if (row < NN) {
                    float vv = fmaxf(a[r] + bv[n], 0.0f);
                    xb[(size_t)row * SLW] = (unsigned short)f2bf(vv);
                }
            }
        }
    }
}

// ---------------------------------------------------------------------------
// Kernel 2: out[i, s*32..s*32+32) = mean_k xs[s][edge[i,k], :].
// Slice s = blockIdx.x & 7 -> pinned to one XCD (round-robin dispatch), whose
// 4MB L2 holds the whole 3.2MB slice. 4 waves/block; wave = 16 nodes;
// lane = node(g=lane>>2) x quad(q=lane&3). Edges: one coalesced int4 per
// lane, distributed via static __shfl. NT stores keep L2 clean.
// ---------------------------------------------------------------------------
__global__ __launch_bounds__(256) void gather_mean(
    const int* __restrict__ edge, const unsigned short* __restrict__ xs,
    float* __restrict__ out)
{
    const int s    = blockIdx.x & 7;
    const int grp  = blockIdx.x >> 3;
    const int lane = threadIdx.x & 63;
    const int w    = threadIdx.x >> 6;
    const int iw0  = grp * 64 + w * 16;
    const int g    = lane >> 2, q = lane & 3;
    const int i    = iw0 + g;

    // wave's 256 contiguous edge ints: lane -> int4 (fully coalesced)
    int eoff = iw0 * KNB + lane * 4;
    if (eoff > NN * KNB - 4) eoff = NN * KNB - 4;
    int4 e4 = *(const int4*)(edge + eoff);
    int e[4] = { e4.x, e4.y, e4.z, e4.w };

    const unsigned short* xsl = xs + (size_t)s * NN * SLW;

    float a[8];
    #pragma unroll
    for (int j = 0; j < 8; ++j) a[j] = 0.0f;

    #pragma unroll
    for (int k = 0; k < KNB; ++k) {
        int src = (lane & 60) | (k >> 2);           // lane holding e[node g][k]
        int n = __shfl(e[k & 3], src, 64);
        bf16x8 v = *(const bf16x8*)(xsl + (size_t)n * SLW + q * 8);
        const unsigned int* vu = (const unsigned int*)&v;
        #pragma unroll
        for (int j = 0; j < 4; ++j) {
            a[2 * j]     += bf2f(vu[j] & 0xffffu);
            a[2 * j + 1] += bf2f_hi(vu[j]);
        }
    }

    if (i < NN) {
        f32x4 o0 = { a[0] * 0.0625f, a[1] * 0.0625f, a[2] * 0.0625f, a[3] * 0.0625f };
        f32x4 o1 = { a[4] * 0.0625f, a[5] * 0.0625f, a[6] * 0.0625f, a[7] * 0.0625f };
        float* op = out + (size_t)i * DD + s * SLW + q * 8;
        __builtin_nontemporal_store(o0, (f32x4*)op);
        __builtin_nontemporal_store(o1, (f32x4*)(op + 4));
    }
}

extern "C" void kernel_launch(void* const* d_in, const int* in_sizes, int n_in,
                              void* d_out, int out_size, void* d_ws, size_t ws_size,
                              hipStream_t stream) {
    // inputs: 0:idx 1:feats 2:edge_dict 3:sadj 4:epoch 5:W 6:b
    const float* feats = (const float*)d_in[1];
    const int*   edge  = (const int*)d_in[2];
    const float* W     = (const float*)d_in[5];
    const float* b     = (const float*)d_in[6];
    float* out = (float*)d_out;

    unsigned short* xs  = (unsigned short*)d_ws;                            // 25.6 MB sliced
    unsigned short* Wbf = (unsigned short*)((char*)d_ws + (size_t)NN * DD * 2); // +128 KB

    const int ngrp = (NN + 63) / 64;   // 782
    convert_w<<<dim3(32), dim3(256), 0, stream>>>(W, Wbf);
    gemm_relu<<<dim3(ngrp), dim3(256), 0, stream>>>(feats, Wbf, b, xs);
    gather_mean<<<dim3(ngrp * NSL), dim3(256), 0, stream>>>(edge, xs, out);
}

// Round 5
// 65.223 us; speedup vs baseline: 1.3871x; 1.3871x over previous
//
#include <hip/hip_runtime.h>
#include <hip/hip_bf16.h>

#define NN  50000
#define DD  256
#define KNB 16
#define BM  64
#define NSL 8      // column slices (one per XCD)
#define SLW 32     // slice width in columns (64B bf16 rows -> line-pure slices)
#define NKT 8      // 256 / 32

typedef __attribute__((ext_vector_type(8))) short bf16x8;
typedef __attribute__((ext_vector_type(4))) float f32x4;

static __device__ __forceinline__ float bf2f(unsigned int u16) {
    union { unsigned int i; float f; } c; c.i = u16 << 16; return c.f;
}
static __device__ __forceinline__ float bf2f_hi(unsigned int u) {
    union { unsigned int i; float f; } c; c.i = u & 0xffff0000u; return c.f;
}
static __device__ __forceinline__ short f2bf(float f) {
    union { float f; unsigned int i; } c; c.f = f;
    unsigned int r = c.i + 0x7FFFu + ((c.i >> 16) & 1u);   // RNE
    return (short)(r >> 16);
}
static __device__ __forceinline__ bf16x8 pack8(float4 a, float4 b) {
    union { __hip_bfloat162 h[4]; bf16x8 v; } u;
    u.h[0] = __float22bfloat162_rn(make_float2(a.x, a.y));
    u.h[1] = __float22bfloat162_rn(make_float2(a.z, a.w));
    u.h[2] = __float22bfloat162_rn(make_float2(b.x, b.y));
    u.h[3] = __float22bfloat162_rn(make_float2(b.z, b.w));
    return u.v;
}

#define GLOAD_LDS16(g, l) \
    __builtin_amdgcn_global_load_lds((const __attribute__((address_space(1))) unsigned int*)(g), \
                                     (__attribute__((address_space(3))) unsigned int*)(l), 16, 0, 0)

// ---------------------------------------------------------------------------
// Kernel 0: W (f32, row-major 256x256) -> bf16 fragment-tiled Wbf.
// slot s = ((kt*16 + nb)*4 + kb)*16 + j  holds 8 bf16:
//   Wbf[s*8 + e] = W[nb*16 + j][kt*32 + kb*8 + e]
// ---------------------------------------------------------------------------
__global__ void convert_w(const float* __restrict__ W, unsigned short* __restrict__ Wbf)
{
    int s = blockIdx.x * blockDim.x + threadIdx.x;   // 8192 slots
    if (s >= 8192) return;
    int j  = s & 15;
    int kb = (s >> 4) & 3;
    int nb = (s >> 6) & 15;
    int kt = s >> 10;
    const float4* p = (const float4*)(W + (nb * 16 + j) * DD + kt * 32 + kb * 8);
    *(bf16x8*)&Wbf[(size_t)s * 8] = pack8(p[0], p[1]);
}

// ---------------------------------------------------------------------------
// Kernel 1: x = relu(feats @ W^T + b) -> bf16 in SLICED layout:
//   xs[(col>>5)*NN*32 + row*32 + (col&31)]
// 256 threads = 4 waves; wave wc owns cols [wc*64, wc*64+64). BM=64, BK=32.
// Double-buffered LDS: A (4 KB, reg-staged f32->bf16 via cvt_pk) + W (16 KB
// via global_load_lds from pre-tiled Wbf). One barrier per K-step.
// LDS = 40 KB -> 4 blocks/CU.
// ---------------------------------------------------------------------------
__global__ __launch_bounds__(256, 4) void gemm_relu(
    const float* __restrict__ feats, const unsigned short* __restrict__ Wbf,
    const float* __restrict__ bias, unsigned short* __restrict__ xs)
{
    __shared__ short At[2][BM * 32];   // [mblk4][kb4][i16][e8]
    __shared__ short Wt[2][8192];      // [nb16][kb4][j16][e8]

    const int tid  = threadIdx.x;
    const int lane = tid & 63;
    const int wc   = tid >> 6;
    const int l15  = lane & 15;
    const int lg   = lane >> 4;
    const int blockRow = blockIdx.x * BM;

    // A staging: thread owns (row = tid>>2, k-quad = tid&3): 8 f32
    const int arow = tid >> 2, akq = tid & 3;
    const int grow = blockRow + arow;
    const bool aval = grow < NN;
    const float* abase = feats + (size_t)grow * DD + akq * 8;
    const int aslot = (((arow >> 4) * 4 + akq) * 16 + (arow & 15)) * 8;

    float4 ra, rb;
    auto aload = [&](int kt) {
        if (aval) {
            const float4* p = (const float4*)(abase + kt * 32);
            ra = p[0]; rb = p[1];
        } else { ra = make_float4(0,0,0,0); rb = ra; }
    };
    auto astore = [&](int buf) {
        *(bf16x8*)&At[buf][aslot] = pack8(ra, rb);
    };
    auto wstage = [&](int kt, int buf) {
        const char* src = (const char*)Wbf + kt * 16384 + tid * 16;
        char* dst = (char*)&Wt[buf][0] + tid * 16;
        #pragma unroll
        for (int c = 0; c < 4; ++c)
            GLOAD_LDS16(src + c * 4096, dst + c * 4096);
    };

    float bv[4];
    #pragma unroll
    for (int n = 0; n < 4; ++n) bv[n] = bias[wc * 64 + n * 16 + l15];

    f32x4 acc[4][4];
    #pragma unroll
    for (int m = 0; m < 4; ++m)
        #pragma unroll
        for (int n = 0; n < 4; ++n) acc[m][n] = (f32x4)0.0f;

    aload(0); wstage(0, 0); astore(0);
    __syncthreads();

    int cur = 0;
    for (int kt = 0; kt < NKT; ++kt) {
        int nxt = cur ^ 1;
        if (kt + 1 < NKT) { aload(kt + 1); wstage(kt + 1, nxt); }

        bf16x8 afr[4], bfr[4];
        #pragma unroll
        for (int m = 0; m < 4; ++m)
            afr[m] = *(const bf16x8*)&At[cur][((m * 4 + lg) * 16 + l15) * 8];
        #pragma unroll
        for (int n = 0; n < 4; ++n)
            bfr[n] = *(const bf16x8*)&Wt[cur][(((wc * 4 + n) * 4 + lg) * 16 + l15) * 8];

        #pragma unroll
        for (int m = 0; m < 4; ++m)
            #pragma unroll
            for (int n = 0; n < 4; ++n)
                acc[m][n] = __builtin_amdgcn_mfma_f32_16x16x32_bf16(
                    afr[m], bfr[n], acc[m][n], 0, 0, 0);

        if (kt + 1 < NKT) astore(nxt);
        __syncthreads();
        cur = nxt;
    }

    // ---- epilogue: bias + relu -> sliced bf16 store ----
    #pragma unroll
    for (int n = 0; n < 4; ++n) {
        const int sl = wc * 2 + (n >> 1);
        const int c  = (n & 1) * 16 + l15;
        unsigned short* xb = xs + (size_t)sl * NN * SLW + c;
        #pragma unroll
        for (int m = 0; m < 4; ++m) {
            int rbase = blockRow + m * 16 + (lg << 2);
            f32x4 a = acc[m][n];
            #pragma unroll
            for (int r = 0; r < 4; ++r) {
                int row = rbase + r;
                if (row < NN) {
                    float vv = fmaxf(a[r] + bv[n], 0.0f);
                    xb[(size_t)row * SLW] = (unsigned short)f2bf(vv);
                }
            }
        }
    }
}

// ---------------------------------------------------------------------------
// Kernel 2: out[i, s*32..s*32+32) = mean_k xs[s][edge[i,k], :].
// Slice s = blockIdx.x & 7 -> pinned to one XCD (round-robin dispatch), whose
// 4MB L2 holds the whole 3.2MB slice. 4 waves/block; wave = 16 nodes;
// lane = node(g=lane>>2) x quad(q=lane&3). Edges: one coalesced int4 per
// lane, distributed via static __shfl. NT stores keep L2 clean.
// ---------------------------------------------------------------------------
__global__ __launch_bounds__(256) void gather_mean(
    const int* __restrict__ edge, const unsigned short* __restrict__ xs,
    float* __restrict__ out)
{
    const int s    = blockIdx.x & 7;
    const int grp  = blockIdx.x >> 3;
    const int lane = threadIdx.x & 63;
    const int w    = threadIdx.x >> 6;
    const int iw0  = grp * 64 + w * 16;
    const int g    = lane >> 2, q = lane & 3;
    const int i    = iw0 + g;

    // wave's 256 contiguous edge ints: lane -> int4 (fully coalesced)
    int eoff = iw0 * KNB + lane * 4;
    if (eoff > NN * KNB - 4) eoff = NN * KNB - 4;
    int4 e4 = *(const int4*)(edge + eoff);
    int e[4] = { e4.x, e4.y, e4.z, e4.w };

    const unsigned short* xsl = xs + (size_t)s * NN * SLW;

    float a[8];
    #pragma unroll
    for (int j = 0; j < 8; ++j) a[j] = 0.0f;

    #pragma unroll
    for (int k = 0; k < KNB; ++k) {
        int src = (lane & 60) | (k >> 2);           // lane holding e[node g][k]
        int n = __shfl(e[k & 3], src, 64);
        bf16x8 v = *(const bf16x8*)(xsl + (size_t)n * SLW + q * 8);
        const unsigned int* vu = (const unsigned int*)&v;
        #pragma unroll
        for (int j = 0; j < 4; ++j) {
            a[2 * j]     += bf2f(vu[j] & 0xffffu);
            a[2 * j + 1] += bf2f_hi(vu[j]);
        }
    }

    if (i < NN) {
        f32x4 o0 = { a[0] * 0.0625f, a[1] * 0.0625f, a[2] * 0.0625f, a[3] * 0.0625f };
        f32x4 o1 = { a[4] * 0.0625f, a[5] * 0.0625f, a[6] * 0.0625f, a[7] * 0.0625f };
        float* op = out + (size_t)i * DD + s * SLW + q * 8;
        __builtin_nontemporal_store(o0, (f32x4*)op);
        __builtin_nontemporal_store(o1, (f32x4*)(op + 4));
    }
}

extern "C" void kernel_launch(void* const* d_in, const int* in_sizes, int n_in,
                              void* d_out, int out_size, void* d_ws, size_t ws_size,
                              hipStream_t stream) {
    // inputs: 0:idx 1:feats 2:edge_dict 3:sadj 4:epoch 5:W 6:b
    const float* feats = (const float*)d_in[1];
    const int*   edge  = (const int*)d_in[2];
    const float* W     = (const float*)d_in[5];
    const float* b     = (const float*)d_in[6];
    float* out = (float*)d_out;

    unsigned short* xs  = (unsigned short*)d_ws;                            // 25.6 MB sliced
    unsigned short* Wbf = (unsigned short*)((char*)d_ws + (size_t)NN * DD * 2); // +128 KB

    const int ngrp = (NN + 63) / 64;   // 782
    convert_w<<<dim3(32), dim3(256), 0, stream>>>(W, Wbf);
    gemm_relu<<<dim3(ngrp), dim3(256), 0, stream>>>(feats, Wbf, b, xs);
    gather_mean<<<dim3(ngrp * NSL), dim3(256), 0, stream>>>(edge, xs, out);
}